// Round 2
// baseline (636.393 us; speedup 1.0000x reference)
//
#include <hip/hip_runtime.h>
#include <math.h>

constexpr int BB   = 2;
constexpr int CC   = 64;
constexpr int HH   = 128;
constexpr int WW   = 128;
constexpr int OO   = 64;
constexpr int HWSZ = HH * WW;    // 16384
constexpr int HOWO = 16384;
constexpr int OMC  = 27;

// ---------------------------------------------------------------------------
// Prep: wt_om [9][64][28] (27 padded to 28), wt_dcn [9][64][64]
// ---------------------------------------------------------------------------
__global__ __launch_bounds__(256) void prep_transpose(
    const float* __restrict__ w_dcn, const float* __restrict__ w_om,
    float* __restrict__ wt_dcn, float* __restrict__ wt_om)
{
    int idx = blockIdx.x * 256 + threadIdx.x;
    if (idx < 9 * 64 * 64) {
        int o  = idx & 63;
        int c  = (idx >> 6) & 63;
        int kk = idx >> 12;
        wt_dcn[idx] = w_dcn[(o * CC + c) * 9 + kk];
    }
    if (idx < 9 * 64 * 28) {
        int o    = idx % 28;
        int rest = idx / 28;
        int c    = rest & 63;
        int kk   = rest >> 6;
        wt_om[idx] = (o < OMC) ? w_om[(o * CC + c) * 9 + kk] : 0.f;
    }
}

// ---------------------------------------------------------------------------
// Fused kernel: block = 32 pixels x 8 c-groups (8 channels each).
// Part A: partial 27-ch conv per thread -> LDS reduce -> offsets (d_out+LDS),
//         sigmoid mask (LDS).
// Part B: deformable conv, v computed once per (kk,c), acc[64] per thread,
//         LDS chunk-reduce over 8 c-groups.
// ---------------------------------------------------------------------------
__global__ __launch_bounds__(256, 4) void fused_dcn_kernel(
    const float* __restrict__ xo,    // input_offset
    const float* __restrict__ xr,    // input_real
    const float* __restrict__ wtom,  // [9][64][28]
    const float* __restrict__ bom,   // [27]
    const float* __restrict__ wtd,   // [9][64][64]
    const float* __restrict__ bd,    // [64]
    float* __restrict__ out,         // [B][64][HoWo]
    float* __restrict__ off_out)     // [B][18][HoWo]
{
    __shared__ float lds_om[8][32][29];   // odd stride: conflict-free
    __shared__ float lds_offm[32][29];    // [pix][0..17]=offset, [18..26]=mask

    const int tid  = threadIdx.x;
    const int pixl = tid & 31;
    const int cg   = tid >> 5;                 // 0..7
    const int pixg = blockIdx.x * 32 + pixl;
    const int b    = pixg >> 14;
    const int p    = pixg & 16383;
    const int p0   = (blockIdx.x * 32) & 16383;
    const int ho   = p >> 7, wo = p & 127;

    // ---------------- Part A: offset/mask conv (partial over 8 channels)
    float oma[28];
#pragma unroll
    for (int j = 0; j < 28; ++j) oma[j] = 0.f;
    {
        const float* xb = xo + (size_t)b * CC * HWSZ;
#pragma unroll 2
        for (int i = 0; i < 8; ++i) {
            const int c = cg * 8 + i;
            const float* xc = xb + c * HWSZ;
            float t[9];
#pragma unroll
            for (int kh = 0; kh < 3; ++kh) {
                const int ih = ho + kh - 1;
                const bool rv = (unsigned)ih < (unsigned)HH;
#pragma unroll
                for (int kw = 0; kw < 3; ++kw) {
                    const int iw = wo + kw - 1;
                    t[kh * 3 + kw] =
                        (rv && (unsigned)iw < (unsigned)WW) ? xc[ih * WW + iw] : 0.f;
                }
            }
#pragma unroll
            for (int kk = 0; kk < 9; ++kk) {
                const float tv = t[kk];
                const float4* wr = (const float4*)(wtom + ((kk << 6) + c) * 28);
#pragma unroll
                for (int q = 0; q < 7; ++q) {
                    const float4 wv = wr[q];
                    oma[q * 4 + 0] += tv * wv.x;
                    oma[q * 4 + 1] += tv * wv.y;
                    oma[q * 4 + 2] += tv * wv.z;
                    oma[q * 4 + 3] += tv * wv.w;
                }
            }
        }
    }
#pragma unroll
    for (int j = 0; j < 28; ++j) lds_om[cg][pixl][j] = oma[j];
    __syncthreads();

    // reduce 8 partials -> offsets/mask
#pragma unroll
    for (int it = 0; it < 4; ++it) {
        const int idx = it * 256 + tid;
        if (idx < 32 * 27) {
            const int pp = idx & 31;
            const int o  = idx >> 5;           // 0..26
            float s = bom[o];
#pragma unroll
            for (int g = 0; g < 8; ++g) s += lds_om[g][pp][o];
            if (o < 18) {
                off_out[(b * 18 + o) * HOWO + p0 + pp] = s;
                lds_offm[pp][o] = s;
            } else {
                lds_offm[pp][o] = 1.f / (1.f + expf(-s));
            }
        }
    }
    __syncthreads();

    // ---------------- Part B: deformable conv, acc over all 64 out channels
    float acc[64];
#pragma unroll
    for (int j = 0; j < 64; ++j) acc[j] = 0.f;

    const float* xrb = xr + (size_t)b * CC * HWSZ;
    for (int kk = 0; kk < 9; ++kk) {
        const float oy = lds_offm[pixl][2 * kk];
        const float ox = lds_offm[pixl][2 * kk + 1];
        const float m  = lds_offm[pixl][18 + kk];

        const int ky = kk / 3, kx = kk - ky * 3;
        const float yf = (float)(ho + ky - 1) + oy;
        const float xf = (float)(wo + kx - 1) + ox;
        const float y0 = floorf(yf), x0 = floorf(xf);
        const float ly = yf - y0, lx = xf - x0;
        const float hy = 1.f - ly, hx = 1.f - lx;
        const int iy0 = (int)y0, ix0 = (int)x0;
        const int iy1 = iy0 + 1, ix1 = ix0 + 1;
        const bool vy0 = (unsigned)iy0 < (unsigned)HH;
        const bool vy1 = (unsigned)iy1 < (unsigned)HH;
        const bool vx0 = (unsigned)ix0 < (unsigned)WW;
        const bool vx1 = (unsigned)ix1 < (unsigned)WW;
        const float w00 = (vy0 && vx0) ? hy * hx * m : 0.f;
        const float w01 = (vy0 && vx1) ? hy * lx * m : 0.f;
        const float w10 = (vy1 && vx0) ? ly * hx * m : 0.f;
        const float w11 = (vy1 && vx1) ? ly * lx * m : 0.f;
        const int cy0 = min(max(iy0, 0), HH - 1), cy1 = min(max(iy1, 0), HH - 1);
        const int cx0 = min(max(ix0, 0), WW - 1), cx1 = min(max(ix1, 0), WW - 1);
        const int i00 = cy0 * WW + cx0, i01 = cy0 * WW + cx1;
        const int i10 = cy1 * WW + cx0, i11 = cy1 * WW + cx1;

#pragma unroll 2
        for (int i = 0; i < 8; ++i) {
            const int c = cg * 8 + i;
            const float* xc = xrb + c * HWSZ;
            const float v = w00 * xc[i00] + w01 * xc[i01] +
                            w10 * xc[i10] + w11 * xc[i11];
            const float4* wr = (const float4*)(wtd + (((kk << 6) + c) << 6));
#pragma unroll
            for (int q = 0; q < 16; ++q) {
                const float4 wv = wr[q];
                acc[q * 4 + 0] += v * wv.x;
                acc[q * 4 + 1] += v * wv.y;
                acc[q * 4 + 2] += v * wv.z;
                acc[q * 4 + 3] += v * wv.w;
            }
        }
    }

    // ---------------- chunked LDS reduce over the 8 c-groups + store
    float* ldsr = &lds_om[0][0][0];           // reuse as [8][32][17]
#pragma unroll 1
    for (int ocq = 0; ocq < 4; ++ocq) {
        __syncthreads();
#pragma unroll
        for (int j = 0; j < 16; ++j)
            ldsr[(cg * 32 + pixl) * 17 + j] = acc[ocq * 16 + j];
        __syncthreads();
        const int pp = tid & 31;
        const int oh = tid >> 5;              // 0..7
#pragma unroll
        for (int u = 0; u < 2; ++u) {
            const int oc = ocq * 16 + oh * 2 + u;
            float s = bd[oc];
#pragma unroll
            for (int g = 0; g < 8; ++g)
                s += ldsr[(g * 32 + pp) * 17 + (oh * 2 + u)];
            out[((size_t)(b * OO + oc)) * HOWO + p0 + pp] = s;
        }
    }
}

// ---------------------------------------------------------------------------
// Slow fallback (round-0, verified): used only if ws_size is too small.
// ---------------------------------------------------------------------------
__global__ __launch_bounds__(256) void conv_om_slow(
    const float* __restrict__ x, const float* __restrict__ w,
    const float* __restrict__ bias, float* __restrict__ off_out)
{
    const int xid = blockIdx.x;
    const int b   = xid >> 6;
    const int p   = ((xid & 63) << 8) + threadIdx.x;
    const int ho  = p >> 7, wo = p & 127;
    const int oc0 = blockIdx.y << 4;

    float acc[16];
#pragma unroll
    for (int j = 0; j < 16; ++j) {
        const int oc = oc0 + j;
        acc[j] = (oc < OMC) ? bias[oc] : 0.f;
    }
    const float* xb = x + (size_t)b * CC * HWSZ;
    for (int c = 0; c < CC; ++c) {
        const float* xc = xb + c * HWSZ;
        float t[9];
#pragma unroll
        for (int kh = 0; kh < 3; ++kh) {
            const int ih = ho + kh - 1;
            const bool rv = (unsigned)ih < (unsigned)HH;
#pragma unroll
            for (int kw = 0; kw < 3; ++kw) {
                const int iw = wo + kw - 1;
                t[kh * 3 + kw] =
                    (rv && (unsigned)iw < (unsigned)WW) ? xc[ih * WW + iw] : 0.f;
            }
        }
#pragma unroll
        for (int j = 0; j < 16; ++j) {
            const int oc = oc0 + j;
            if (oc < OMC) {
                const float* wj = w + (size_t)(oc * CC + c) * 9;
                float s = 0.f;
#pragma unroll
                for (int kk = 0; kk < 9; ++kk) s += t[kk] * wj[kk];
                acc[j] += s;
            }
        }
    }
#pragma unroll
    for (int j = 0; j < 16; ++j) {
        const int oc = oc0 + j;
        if (oc < 18) off_out[(b * 18 + oc) * HOWO + p] = acc[j];
    }
}

__global__ __launch_bounds__(256) void dcn_slow(
    const float* __restrict__ xr, const float* __restrict__ off,
    const float* __restrict__ wd, const float* __restrict__ bd,
    float* __restrict__ out, const float* __restrict__ xo,
    const float* __restrict__ wom, const float* __restrict__ bom)
{
    const int xid = blockIdx.x;
    const int b   = xid >> 6;
    const int p   = ((xid & 63) << 8) + threadIdx.x;
    const int ho  = p >> 7, wo = p & 127;
    const int o0  = blockIdx.y << 4;

    float acc[16];
#pragma unroll
    for (int j = 0; j < 16; ++j) acc[j] = bd[o0 + j];
    const float* xb = xr + (size_t)b * CC * HWSZ;

    for (int kk = 0; kk < 9; ++kk) {
        const float oy = off[(b * 18 + 2 * kk) * HOWO + p];
        const float ox = off[(b * 18 + 2 * kk + 1) * HOWO + p];
        float a = bom[18 + kk];
        const float* xob = xo + (size_t)b * CC * HWSZ;
        for (int c = 0; c < CC; ++c) {
            const float* xc2 = xob + c * HWSZ;
            const float* wj  = wom + (size_t)((18 + kk) * CC + c) * 9;
#pragma unroll
            for (int kh = 0; kh < 3; ++kh) {
                const int ih = ho + kh - 1;
                if ((unsigned)ih < (unsigned)HH) {
#pragma unroll
                    for (int kw = 0; kw < 3; ++kw) {
                        const int iw = wo + kw - 1;
                        if ((unsigned)iw < (unsigned)WW)
                            a += xc2[ih * WW + iw] * wj[kh * 3 + kw];
                    }
                }
            }
        }
        const float m = 1.f / (1.f + expf(-a));

        const int ky = kk / 3, kx = kk - ky * 3;
        const float yf = (float)(ho + ky - 1) + oy;
        const float xf = (float)(wo + kx - 1) + ox;
        const float y0 = floorf(yf), x0 = floorf(xf);
        const float ly = yf - y0, lx = xf - x0;
        const float hy = 1.f - ly, hx = 1.f - lx;
        const int iy0 = (int)y0, ix0 = (int)x0;
        const int iy1 = iy0 + 1, ix1 = ix0 + 1;
        const bool vy0 = (unsigned)iy0 < (unsigned)HH;
        const bool vy1 = (unsigned)iy1 < (unsigned)HH;
        const bool vx0 = (unsigned)ix0 < (unsigned)WW;
        const bool vx1 = (unsigned)ix1 < (unsigned)WW;
        const float w00 = (vy0 && vx0) ? hy * hx * m : 0.f;
        const float w01 = (vy0 && vx1) ? hy * lx * m : 0.f;
        const float w10 = (vy1 && vx0) ? ly * hx * m : 0.f;
        const float w11 = (vy1 && vx1) ? ly * lx * m : 0.f;
        const int cy0 = min(max(iy0, 0), HH - 1), cy1 = min(max(iy1, 0), HH - 1);
        const int cx0 = min(max(ix0, 0), WW - 1), cx1 = min(max(ix1, 0), WW - 1);
        const int i00 = cy0 * WW + cx0, i01 = cy0 * WW + cx1;
        const int i10 = cy1 * WW + cx0, i11 = cy1 * WW + cx1;

#pragma unroll 4
        for (int c = 0; c < CC; ++c) {
            const float* xc = xb + c * HWSZ;
            const float v = w00 * xc[i00] + w01 * xc[i01] +
                            w10 * xc[i10] + w11 * xc[i11];
#pragma unroll
            for (int j = 0; j < 16; ++j)
                acc[j] += v * wd[(size_t)((o0 + j) * CC + c) * 9 + kk];
        }
    }
#pragma unroll
    for (int j = 0; j < 16; ++j)
        out[((size_t)b * OO + o0 + j) * HOWO + p] = acc[j];
}

// ---------------------------------------------------------------------------
extern "C" void kernel_launch(void* const* d_in, const int* in_sizes, int n_in,
                              void* d_out, int out_size, void* d_ws, size_t ws_size,
                              hipStream_t stream)
{
    const float* x_off  = (const float*)d_in[0];
    const float* x_real = (const float*)d_in[1];
    const float* w_om   = (const float*)d_in[2];
    const float* b_om   = (const float*)d_in[3];
    const float* w_dcn  = (const float*)d_in[4];
    const float* b_dcn  = (const float*)d_in[5];

    float* out = (float*)d_out;
    const int outElems = BB * OO * HOWO;
    float* off_out = out + outElems;              // [B][18][HoWo]

    const size_t wtDcnFloats = 9 * 64 * 64;       // 36864
    const size_t wtOmFloats  = 9 * 64 * 28;       // 16128
    const size_t need = (wtDcnFloats + wtOmFloats) * sizeof(float);

    if (ws_size >= need) {
        float* wtDcn = (float*)d_ws;
        float* wtOm  = wtDcn + wtDcnFloats;
        hipLaunchKernelGGL(prep_transpose, dim3(144), dim3(256), 0, stream,
                           w_dcn, w_om, wtDcn, wtOm);
        hipLaunchKernelGGL(fused_dcn_kernel, dim3(1024), dim3(256), 0, stream,
                           x_off, x_real, wtOm, b_om, wtDcn, b_dcn,
                           out, off_out);
    } else {
        hipLaunchKernelGGL(conv_om_slow, dim3(128, 2), dim3(256), 0, stream,
                           x_off, w_om, b_om, off_out);
        hipLaunchKernelGGL(dcn_slow, dim3(128, 4), dim3(256), 0, stream,
                           x_real, off_out, w_dcn, b_dcn, out,
                           x_off, w_om, b_om);
    }
}